// Round 10
// baseline (185.589 us; speedup 1.0000x reference)
//
#include <hip/hip_runtime.h>
#include <math.h>

typedef __attribute__((ext_vector_type(8))) short bf16x8;
typedef __attribute__((ext_vector_type(4))) float f32x4;

// ================= compile-time Clebsch-Gordan tables =================
constexpr double cfact(int n){ double r=1.0; for(int i=2;i<=n;++i) r*=(double)i; return r; }
constexpr double csqrt_(double x){ double g=(x>1.0)?x:1.0; for(int i=0;i<100;++i) g=0.5*(g+x/g); return g; }
constexpr double cg_coef_(int l1,int m1,int l2,int m2,int l,int m){
  double pre = csqrt_((double)(2*l+1)*cfact(l1+l2-l)*cfact(l1-l2+l)*cfact(-l1+l2+l)/cfact(l1+l2+l+1));
  pre = pre*csqrt_(cfact(l+m)*cfact(l-m)*cfact(l1-m1)*cfact(l1+m1)*cfact(l2-m2)*cfact(l2+m2));
  double s=0.0;
  for(int k=0;k<=l1+l2-l;++k){
    int d0=k,d1=l1+l2-l-k,d2=l1-m1-k,d3=l2+m2-k,d4=l-l2+m1+k,d5=l-l1-m2+k;
    if(d0<0||d1<0||d2<0||d3<0||d4<0||d5<0) continue;
    double den=cfact(d0)*cfact(d1)*cfact(d2)*cfact(d3)*cfact(d4)*cfact(d5);
    s+=((k&1)?-1.0:1.0)/den;
  }
  return pre*s;
}
struct CGList{ int n; float coef[64]; int mi[64]; int ni[64]; int pi[64]; };
constexpr CGList build_cg(int l1,int l2,int l){
  CGList T{};
  for(int i=0;i<2*l1+1;++i){
    for(int j=0;j<2*l2+1;++j){
      int m1=i-l1, m2=j-l2, m=m1+m2;
      if(m<-l||m>l) continue;
      double c=cg_coef_(l1,m1,l2,m2,l,m);
      if(c>1e-12||c<-1e-12){
        T.coef[T.n]=(float)c; T.mi[T.n]=i; T.ni[T.n]=j; T.pi[T.n]=m+l; T.n++;
      }
    }
  }
  return T;
}

// ================= layout constants =================
__device__ __host__ constexpr int AOFF(int l){ return l==0?0: l==1?16: l==2?64:144; }
__device__ __host__ constexpr int MLs(int l){ return l==0?1024: l==1?1536: l==2?1792:1536; }
__device__ __host__ constexpr int WOFF(int l){ return l==0?0: l==1?16384: l==2?40960:69632; }
__device__ __host__ constexpr int SOFF(int l){ return l==0?0: l==1?1024: l==2?2560:4352; }
__device__ __host__ constexpr int NTRI(int l){ return l==0?4: l==1?6: l==2?7:6; }
__device__ __host__ constexpr int ABASE(int l){ return l==0?0: l==1?65536: l==2?163840:278528; }
// mid storage (LINEAR): per-l base in 4B words; word = n*Ml + c, n = b*NP+p.
__device__ __host__ constexpr size_t MBW(int l){ return l==0?0 : l==1?2097152 : l==2?11534336 : 29884416; }
#define MID_OFF 1048576
#define MID_BYTES ((size_t)51904512*4)

#define DEVFN __device__ __forceinline__
#define LPITCH 144   // fallback-path LDS pitch
#define APITCH 132   // gemm LDS A-panel row pitch (words): even bank spread

DEVFN unsigned f2bf2(float x, float y){
  unsigned ux = __float_as_uint(x); ux = (ux + 0x7FFFu + ((ux>>16)&1u)) >> 16;
  unsigned uy = __float_as_uint(y); uy = (uy + 0x7FFFu + ((uy>>16)&1u)) >> 16;
  return (ux & 0xFFFFu) | (uy << 16);
}

template<int L1,int L2,int L>
DEVFN void cg_accum(const float2* F1, const float2* F2, float2* mid){
  constexpr CGList T = build_cg(L1,L2,L);
  #pragma unroll
  for(int e=0;e<T.n;++e){
    const float c = T.coef[e];
    const float2 a = F1[T.mi[e]];
    const float2 b = F2[T.ni[e]];
    float pr = a.x*b.x - a.y*b.y;
    float pim= a.x*b.y + a.y*b.x;
    mid[T.pi[e]].x += c*pr;
    mid[T.pi[e]].y += c*pim;
  }
}

// ===== K1: LDS-staged act; channels (2u,2u+1) share F1; NT 8B mid stores =====
template<int L1,int L2,int L,int Q>
DEVFN void k1_body(const float2* __restrict__ acts, int b0, int u, int bh,
                   float& ssa, float& ssb, unsigned* __restrict__ midw){
  constexpr int N1=2*L1+1, N2=2*L2+1, NP=2*L+1, Ml=MLs(L);
  const int t = u>>3, s0 = (u&7)*2;
  unsigned* midq = midw ? (midw + MBW(L) + (size_t)Q*256) : nullptr;
  #pragma unroll 2
  for(int bi=0;bi<8;++bi){
    const int row = bh*8 + bi;
    const float2* arow = acts + row*256;
    float2 F1[N1], F2a[N2], F2b[N2], mida[NP], midb[NP];
    #pragma unroll
    for(int m=0;m<N1;++m) F1[m]=arow[AOFF(L1)+t*N1+m];
    #pragma unroll
    for(int n=0;n<N2;++n){
      F2a[n]=arow[AOFF(L2)+s0*N2+n];
      F2b[n]=arow[AOFF(L2)+(s0+1)*N2+n];
    }
    #pragma unroll
    for(int p=0;p<NP;++p){ mida[p]=make_float2(0.f,0.f); midb[p]=make_float2(0.f,0.f); }
    cg_accum<L1,L2,L>(F1,F2a,mida);
    cg_accum<L1,L2,L>(F1,F2b,midb);
    #pragma unroll
    for(int p=0;p<NP;++p){
      ssa += mida[p].x*mida[p].x + mida[p].y*mida[p].y;
      ssb += midb[p].x*midb[p].x + midb[p].y*midb[p].y;
    }
    if(midq){
      const size_t nrow = (size_t)(b0+row)*NP;
      #pragma unroll
      for(int p=0;p<NP;++p){
        unsigned lo = f2bf2(mida[p].x, mida[p].y);
        unsigned hi = f2bf2(midb[p].x, midb[p].y);
        unsigned long long pv = (unsigned long long)lo | ((unsigned long long)hi<<32);
        __builtin_nontemporal_store(pv, (unsigned long long*)(midq + (nrow+p)*Ml) + u);
      }
    }
  }
}

__global__ __launch_bounds__(256) void k_sumsq(const float* __restrict__ act,
                                               float* __restrict__ sumsq,
                                               unsigned* __restrict__ midw){
  __shared__ float2 acts[16*256];            // 32 KB: 16 act rows
  int bid=blockIdx.x;                        // 23 triples * 128 chunks
  const int order[23] = {22,16,21,18,15,20,13,9,14,8,17,7,12,6,10,3,5,19,2,11,1,4,0};
  int ti = order[bid>>7];
  int b0 = (bid&127)*16;
  const int tid = threadIdx.x;
  {
    const float4* ag = (const float4*)act + (size_t)b0*128;
    float4* as4 = (float4*)acts;
    #pragma unroll
    for(int j=0;j<8;++j) as4[j*256+tid] = ag[j*256+tid];
  }
  __syncthreads();
  const int u = tid & 127, bh = tid >> 7;    // channels (2u,2u+1), b-half bh
  float ssa=0.f, ssb=0.f;
  switch(ti){
    case 0:  k1_body<0,0,0,0>(acts,b0,u,bh,ssa,ssb,midw); break;
    case 1:  k1_body<1,1,0,1>(acts,b0,u,bh,ssa,ssb,midw); break;
    case 2:  k1_body<2,2,0,2>(acts,b0,u,bh,ssa,ssb,midw); break;
    case 3:  k1_body<3,3,0,3>(acts,b0,u,bh,ssa,ssb,midw); break;
    case 4:  k1_body<1,0,1,0>(acts,b0,u,bh,ssa,ssb,midw); break;
    case 5:  k1_body<1,1,1,1>(acts,b0,u,bh,ssa,ssb,midw); break;
    case 6:  k1_body<2,1,1,2>(acts,b0,u,bh,ssa,ssb,midw); break;
    case 7:  k1_body<2,2,1,3>(acts,b0,u,bh,ssa,ssb,midw); break;
    case 8:  k1_body<3,2,1,4>(acts,b0,u,bh,ssa,ssb,midw); break;
    case 9:  k1_body<3,3,1,5>(acts,b0,u,bh,ssa,ssb,midw); break;
    case 10: k1_body<1,1,2,0>(acts,b0,u,bh,ssa,ssb,midw); break;
    case 11: k1_body<2,0,2,1>(acts,b0,u,bh,ssa,ssb,midw); break;
    case 12: k1_body<2,1,2,2>(acts,b0,u,bh,ssa,ssb,midw); break;
    case 13: k1_body<2,2,2,3>(acts,b0,u,bh,ssa,ssb,midw); break;
    case 14: k1_body<3,1,2,4>(acts,b0,u,bh,ssa,ssb,midw); break;
    case 15: k1_body<3,2,2,5>(acts,b0,u,bh,ssa,ssb,midw); break;
    case 16: k1_body<3,3,2,6>(acts,b0,u,bh,ssa,ssb,midw); break;
    case 17: k1_body<2,1,3,0>(acts,b0,u,bh,ssa,ssb,midw); break;
    case 18: k1_body<2,2,3,1>(acts,b0,u,bh,ssa,ssb,midw); break;
    case 19: k1_body<3,0,3,2>(acts,b0,u,bh,ssa,ssb,midw); break;
    case 20: k1_body<3,1,3,3>(acts,b0,u,bh,ssa,ssb,midw); break;
    case 21: k1_body<3,2,3,4>(acts,b0,u,bh,ssa,ssb,midw); break;
    default: k1_body<3,3,3,5>(acts,b0,u,bh,ssa,ssb,midw); break;
  }
  atomicAdd(&sumsq[ti*256 + 2*u],     ssa);
  atomicAdd(&sumsq[ti*256 + 2*u + 1], ssb);
}

// ============ K2: scale + build bf16 A matrices (scale folded into W) =======
__global__ __launch_bounds__(256) void k_buildA(const float* __restrict__ W,
                                                const float* __restrict__ bn,
                                                const float* __restrict__ sumsq,
                                                short* __restrict__ A){
  int idx = blockIdx.x*256 + threadIdx.x;   // 5888 channels
  if(idx>=5888) return;
  int l = (idx<1024)?0 : (idx<2560)?1 : (idx<4352)?2 : 3;
  float divi = (l==0)?(1.f/2048.f) : (l==1)?(1.f/6144.f) : (l==2)?(1.f/10240.f) : (1.f/14336.f);
  float bstd = sqrtf(sumsq[idx]*divi);
  float nstd = 0.5f*(bn[idx]+bstd);
  float s = 1.f/(nstd+1e-5f);
  int c = idx - SOFF(l);
  int Ml = MLs(l);
  const float2* wbase = (const float2*)W + WOFF(l) + c;
  unsigned* Aw = (unsigned*)(A + ABASE(l));   // row pitch = Ml words (2*Ml bf16)
  for(int o=0;o<16;++o){
    float2 w = wbase[(size_t)o*Ml];
    Aw[(size_t)o*Ml + c]      = f2bf2(w.x*s, -w.y*s);
    Aw[(size_t)(o+16)*Ml + c] = f2bf2(w.y*s,  w.x*s);
  }
}

// ======== K5: panel GEMM with register-dbuf B prefetch + NT loads ========
// Block (256 thr, 4 waves) = 4 n-tiles × full K. A panels (256 k-cols,
// 16 KB) double-buffered in LDS; B fragments register-double-buffered and
// prefetched BEFORE the panel barrier so the vmcnt drain overlaps compute.
template<int L>
DEVFN void k5_panel(int tg, const unsigned* __restrict__ midl,
                    const short* __restrict__ A_l, float* __restrict__ out,
                    unsigned* ldsA){
  constexpr int NP = 2*L+1;
  constexpr int Ml = MLs(L);
  constexpr int NK = Ml/16;                  // 32-k chunks (64/96/112/96)
  constexpr int P  = NK/8;                   // panels (8/12/14/12)
  const int tid = threadIdx.x;               // 0..255
  const int lane = tid & 63, w = tid >> 6;
  const int col = lane & 15, quad = lane >> 4;
  const int nt = tg*4 + w;
  const unsigned* Aw = (const unsigned*)A_l;             // word view, pitch Ml
  const unsigned* bp = midl + (size_t)(nt*16 + col)*Ml + quad*4;

  f32x4 cR = {0.f,0.f,0.f,0.f};
  f32x4 cI = {0.f,0.f,0.f,0.f};

  // initial A panel stage (4 subpasses of 16B/thread)
  #pragma unroll
  for(int sub=0;sub<4;++sub){
    int idx = sub*256 + tid, r = idx>>5, j = (idx&31)*4;
    *(uint4*)(ldsA + r*APITCH + j) = *(const uint4*)(Aw + (size_t)r*Ml + j);
  }
  // initial B panel into registers
  bf16x8 b0[8], b1[8];
  #pragma unroll
  for(int c=0;c<8;++c) b0[c] = __builtin_nontemporal_load((const bf16x8*)(bp + c*16));
  __syncthreads();

  #pragma unroll
  for(int p=0;p<P;++p){
    bf16x8* bc = (p&1)? b1 : b0;
    bf16x8* bn = (p&1)? b0 : b1;
    if(p+1 < P){
      #pragma unroll
      for(int c=0;c<8;++c)
        bn[c] = __builtin_nontemporal_load((const bf16x8*)(bp + (p+1)*128 + c*16));
    }
    uint4 v[4];
    if(p+1 < P){
      #pragma unroll
      for(int sub=0;sub<4;++sub){
        int idx = sub*256 + tid, r = idx>>5, j = (idx&31)*4;
        v[sub] = *(const uint4*)(Aw + (size_t)r*Ml + (p+1)*128 + j);
      }
    }
    const unsigned* buf = ldsA + (p&1)*(32*APITCH);
    const unsigned* a0 = buf + col*APITCH + quad*4;
    const unsigned* a1 = buf + (col+16)*APITCH + quad*4;
    #pragma unroll
    for(int c=0;c<8;++c){
      bf16x8 A0 = *(const bf16x8*)(a0 + c*16);
      bf16x8 A1 = *(const bf16x8*)(a1 + c*16);
      cR = __builtin_amdgcn_mfma_f32_16x16x32_bf16(A0, bc[c], cR, 0, 0, 0);
      cI = __builtin_amdgcn_mfma_f32_16x16x32_bf16(A1, bc[c], cI, 0, 0, 0);
    }
    if(p+1 < P){
      unsigned* nbuf = ldsA + ((p+1)&1)*(32*APITCH);
      #pragma unroll
      for(int sub=0;sub<4;++sub){
        int idx = sub*256 + tid, r = idx>>5, j = (idx&31)*4;
        *(uint4*)(nbuf + r*APITCH + j) = v[sub];
      }
    }
    __syncthreads();
  }
  const int n = nt*16 + col;
  const int b = n / NP, pp = n % NP;
  float2* out2 = (float2*)out;
  #pragma unroll
  for(int i=0;i<4;++i){
    const int o = quad*4 + i;
    out2[(size_t)b*256 + AOFF(L) + o*NP + pp] = make_float2(cR[i], cI[i]);
  }
}

__global__ __launch_bounds__(256) void k_gemm5(const unsigned* __restrict__ midw,
                                               const short* __restrict__ A,
                                               float* __restrict__ out){
  __shared__ unsigned ldsA[2*32*APITCH];     // 33792 B dbuf
  const int bid = blockIdx.x;                // 512 = 32(l0)+96(l1)+160(l2)+224(l3)
  if(bid < 32)       k5_panel<0>(bid,       midw+MBW(0), A+ABASE(0), out, ldsA);
  else if(bid < 128) k5_panel<1>(bid - 32,  midw+MBW(1), A+ABASE(1), out, ldsA);
  else if(bid < 288) k5_panel<2>(bid - 128, midw+MBW(2), A+ABASE(2), out, ldsA);
  else               k5_panel<3>(bid - 288, midw+MBW(3), A+ABASE(3), out, ldsA);
}

// ======== fallback (ws too small): recompute-GEMM, unchanged ========
template<int L1,int L2,int L>
DEVFN void phase1(const float2* __restrict__ act2, unsigned* ldsw,
                  int half, int c0, int bh4, int b_lo, int b_hi, int n0){
  constexpr int N1=2*L1+1, N2=2*L2+1, NP=2*L+1;
  const int s  = c0 & 15;
  const int t1 = half*8 + (c0>>4);
  const int t2 = t1 + 4;
  for(int b = b_lo + bh4; b <= b_hi; b += 4){
    const float2* arow = act2 + (size_t)b*256;
    float2 F1a[N1], F1b[N1], F2[N2], mida[NP], midb[NP];
    #pragma unroll
    for(int m=0;m<N1;++m){
      F1a[m]=arow[AOFF(L1)+t1*N1+m];
      F1b[m]=arow[AOFF(L1)+t2*N1+m];
    }
    #pragma unroll
    for(int n=0;n<N2;++n) F2[n]=arow[AOFF(L2)+s*N2+n];
    #pragma unroll
    for(int p=0;p<NP;++p){ mida[p]=make_float2(0.f,0.f); midb[p]=make_float2(0.f,0.f); }
    cg_accum<L1,L2,L>(F1a,F2,mida);
    cg_accum<L1,L2,L>(F1b,F2,midb);
    int nb = b*NP - n0;
    #pragma unroll
    for(int p=0;p<NP;++p){
      int n = nb + p;
      if(n>=0 && n<32){
        ldsw[n*LPITCH + c0]      = f2bf2(mida[p].x, mida[p].y);
        ldsw[n*LPITCH + c0 + 64] = f2bf2(midb[p].x, midb[p].y);
      }
    }
  }
}

template<int L>
DEVFN void p1_dispatch(int q, int half, const float2* __restrict__ act2, unsigned* ldsw,
                       int c0,int bh4,int b_lo,int b_hi,int n0){
  if constexpr(L==0){
    switch(q){
      case 0: phase1<0,0,0>(act2,ldsw,half,c0,bh4,b_lo,b_hi,n0); break;
      case 1: phase1<1,1,0>(act2,ldsw,half,c0,bh4,b_lo,b_hi,n0); break;
      case 2: phase1<2,2,0>(act2,ldsw,half,c0,bh4,b_lo,b_hi,n0); break;
      default:phase1<3,3,0>(act2,ldsw,half,c0,bh4,b_lo,b_hi,n0); break;
    }
  } else if constexpr(L==1){
    switch(q){
      case 0: phase1<1,0,1>(act2,ldsw,half,c0,bh4,b_lo,b_hi,n0); break;
      case 1: phase1<1,1,1>(act2,ldsw,half,c0,bh4,b_lo,b_hi,n0); break;
      case 2: phase1<2,1,1>(act2,ldsw,half,c0,bh4,b_lo,b_hi,n0); break;
      case 3: phase1<2,2,1>(act2,ldsw,half,c0,bh4,b_lo,b_hi,n0); break;
      case 4: phase1<3,2,1>(act2,ldsw,half,c0,bh4,b_lo,b_hi,n0); break;
      default:phase1<3,3,1>(act2,ldsw,half,c0,bh4,b_lo,b_hi,n0); break;
    }
  } else if constexpr(L==2){
    switch(q){
      case 0: phase1<1,1,2>(act2,ldsw,half,c0,bh4,b_lo,b_hi,n0); break;
      case 1: phase1<2,0,2>(act2,ldsw,half,c0,bh4,b_lo,b_hi,n0); break;
      case 2: phase1<2,1,2>(act2,ldsw,half,c0,bh4,b_lo,b_hi,n0); break;
      case 3: phase1<2,2,2>(act2,ldsw,half,c0,bh4,b_lo,b_hi,n0); break;
      case 4: phase1<3,1,2>(act2,ldsw,half,c0,bh4,b_lo,b_hi,n0); break;
      case 5: phase1<3,2,2>(act2,ldsw,half,c0,bh4,b_lo,b_hi,n0); break;
      default:phase1<3,3,2>(act2,ldsw,half,c0,bh4,b_lo,b_hi,n0); break;
    }
  } else {
    switch(q){
      case 0: phase1<2,1,3>(act2,ldsw,half,c0,bh4,b_lo,b_hi,n0); break;
      case 1: phase1<2,2,3>(act2,ldsw,half,c0,bh4,b_lo,b_hi,n0); break;
      case 2: phase1<3,0,3>(act2,ldsw,half,c0,bh4,b_lo,b_hi,n0); break;
      case 3: phase1<3,1,3>(act2,ldsw,half,c0,bh4,b_lo,b_hi,n0); break;
      case 4: phase1<3,2,3>(act2,ldsw,half,c0,bh4,b_lo,b_hi,n0); break;
      default:phase1<3,3,3>(act2,ldsw,half,c0,bh4,b_lo,b_hi,n0); break;
    }
  }
}

template<int L>
DEVFN void k3_gemm(int n0, const float2* __restrict__ act2,
                   const short* __restrict__ A_l, float* __restrict__ out,
                   unsigned* lds){
  constexpr int NP = 2*L+1;
  constexpr int NT = NTRI(L);
  constexpr int pitchA = 2*MLs(L);
  const int tid = threadIdx.x;
  const int lane = tid & 63, wsub = tid >> 6;
  const int col = lane & 15, quad = lane >> 4;
  const int nh = wsub & 1, mh = wsub >> 1;
  const int c0 = tid & 63, bh4 = tid >> 6;
  const int b_lo = n0 / NP;
  const int b_hi = (n0 + 31) / NP;

  f32x4 acc = {0.f,0.f,0.f,0.f};
  const short* Ar = A_l + (size_t)(col + mh*16) * pitchA + quad*8;
  const int lds_rd = (nh*16 + col)*LPITCH + quad*4;

  for(int chunk = 0; chunk < 2*NT; ++chunk){
    const int q = chunk >> 1, half = chunk & 1;
    unsigned* buf = lds + (chunk & 1)*(32*LPITCH);
    p1_dispatch<L>(q, half, act2, buf, c0, bh4, b_lo, b_hi, n0);
    __syncthreads();
    const int kbase = q*512 + half*256;
    const char* ldsb = (const char*)(buf + lds_rd);
    #pragma unroll
    for(int ks=0; ks<8; ++ks){
      bf16x8 a = *(const bf16x8*)(Ar + kbase + ks*32);
      bf16x8 b = *(const bf16x8*)(ldsb + ks*64);
      acc = __builtin_amdgcn_mfma_f32_16x16x32_bf16(a, b, acc, 0, 0, 0);
    }
  }
  const int n = n0 + nh*16 + col;
  const int b = n / NP, p = n % NP;
  #pragma unroll
  for(int i=0;i<4;++i){
    const int o = quad*4 + i;
    out[((size_t)b*256 + AOFF(L) + o*NP + p)*2 + mh] = acc[i];
  }
}

__global__ __launch_bounds__(256) void k_gemm(const float* __restrict__ act,
                                              const short* __restrict__ A,
                                              float* __restrict__ out){
  __shared__ unsigned lds[2*32*LPITCH];
  const int bid = blockIdx.x;
  const float2* act2 = (const float2*)act;
  if(bid < 64)       k3_gemm<0>((bid      )*32, act2, A + ABASE(0), out, lds);
  else if(bid < 256) k3_gemm<1>((bid - 64 )*32, act2, A + ABASE(1), out, lds);
  else if(bid < 576) k3_gemm<2>((bid - 256)*32, act2, A + ABASE(2), out, lds);
  else               k3_gemm<3>((bid - 576)*32, act2, A + ABASE(3), out, lds);
}

// ================= host launch =================
extern "C" void kernel_launch(void* const* d_in, const int* in_sizes, int n_in,
                              void* d_out, int out_size, void* d_ws, size_t ws_size,
                              hipStream_t stream) {
  const float* act = (const float*)d_in[0];   // (2048,256,2) f32
  const float* W   = (const float*)d_in[1];   // (94208,2) f32
  const float* bn  = (const float*)d_in[2];   // (5888,) f32
  float* out = (float*)d_out;                 // (2048,256,2) f32

  float* sumsq = (float*)d_ws;                          // 5888 f32
  short* A     = (short*)((char*)d_ws + 24576);         // 376832 bf16 (754 KB)
  const size_t REQ = (size_t)MID_OFF + MID_BYTES;       // ~209 MB
  unsigned* midw = (ws_size >= REQ) ? (unsigned*)((char*)d_ws + MID_OFF) : nullptr;

  hipMemsetAsync(sumsq, 0, 5888*sizeof(float), stream);
  hipLaunchKernelGGL(k_sumsq,  dim3(23*128), dim3(256), 0, stream, act, sumsq, midw);
  hipLaunchKernelGGL(k_buildA, dim3(23),     dim3(256), 0, stream, W, bn, sumsq, A);
  if(midw)
    hipLaunchKernelGGL(k_gemm5, dim3(512),  dim3(256), 0, stream, (const unsigned*)midw, A, out);
  else
    hipLaunchKernelGGL(k_gemm,  dim3(1024), dim3(256), 0, stream, act, A, out);
}

// Round 11
// 179.666 us; speedup vs baseline: 1.0330x; 1.0330x over previous
//
#include <hip/hip_runtime.h>
#include <math.h>

typedef __attribute__((ext_vector_type(8))) short bf16x8;
typedef __attribute__((ext_vector_type(4))) float f32x4;

// ================= compile-time Clebsch-Gordan tables =================
constexpr double cfact(int n){ double r=1.0; for(int i=2;i<=n;++i) r*=(double)i; return r; }
constexpr double csqrt_(double x){ double g=(x>1.0)?x:1.0; for(int i=0;i<100;++i) g=0.5*(g+x/g); return g; }
constexpr double cg_coef_(int l1,int m1,int l2,int m2,int l,int m){
  double pre = csqrt_((double)(2*l+1)*cfact(l1+l2-l)*cfact(l1-l2+l)*cfact(-l1+l2+l)/cfact(l1+l2+l+1));
  pre = pre*csqrt_(cfact(l+m)*cfact(l-m)*cfact(l1-m1)*cfact(l1+m1)*cfact(l2-m2)*cfact(l2+m2));
  double s=0.0;
  for(int k=0;k<=l1+l2-l;++k){
    int d0=k,d1=l1+l2-l-k,d2=l1-m1-k,d3=l2+m2-k,d4=l-l2+m1+k,d5=l-l1-m2+k;
    if(d0<0||d1<0||d2<0||d3<0||d4<0||d5<0) continue;
    double den=cfact(d0)*cfact(d1)*cfact(d2)*cfact(d3)*cfact(d4)*cfact(d5);
    s+=((k&1)?-1.0:1.0)/den;
  }
  return pre*s;
}
struct CGList{ int n; float coef[64]; int mi[64]; int ni[64]; int pi[64]; };
constexpr CGList build_cg(int l1,int l2,int l){
  CGList T{};
  for(int i=0;i<2*l1+1;++i){
    for(int j=0;j<2*l2+1;++j){
      int m1=i-l1, m2=j-l2, m=m1+m2;
      if(m<-l||m>l) continue;
      double c=cg_coef_(l1,m1,l2,m2,l,m);
      if(c>1e-12||c<-1e-12){
        T.coef[T.n]=(float)c; T.mi[T.n]=i; T.ni[T.n]=j; T.pi[T.n]=m+l; T.n++;
      }
    }
  }
  return T;
}

// ================= layout constants =================
__device__ __host__ constexpr int AOFF(int l){ return l==0?0: l==1?16: l==2?64:144; }
__device__ __host__ constexpr int MLs(int l){ return l==0?1024: l==1?1536: l==2?1792:1536; }
__device__ __host__ constexpr int WOFF(int l){ return l==0?0: l==1?16384: l==2?40960:69632; }
__device__ __host__ constexpr int SOFF(int l){ return l==0?0: l==1?1024: l==2?2560:4352; }
// symmetry-packed mid: l1==l2 triples store only t<=s (136 of 256 channels)
__device__ __host__ constexpr int MLP_(int l){ return l==0?544: l==1?1184: l==2?1440:1296; }
__device__ __host__ constexpr size_t MBW(int l){ return l==0?0 : l==1?1114112 : l==2?8388608 : 23134208; }
#define MID_OFF 1048576
#define MID_BYTES ((size_t)41713664*4)
__device__ __host__ constexpr int PAW(int l){ return l==0?640: l==1?1280: l==2?1536:1408; }
__device__ __host__ constexpr int ABW(int l){ return l==0?0: l==1?20480: l==2?61440:110592; }
#define A_WORDS 155648
__device__ __host__ constexpr int NKc(int l){ return MLP_(l)/16; }   // 34/74/90/81
__device__ __host__ constexpr int PNc(int l){ return (NKc(l)+7)/8; } // 5/10/12/11

#define DEVFN __device__ __forceinline__
#define APITCH 132

DEVFN unsigned f2bf2(float x, float y){
  unsigned ux = __float_as_uint(x); ux = (ux + 0x7FFFu + ((ux>>16)&1u)) >> 16;
  unsigned uy = __float_as_uint(y); uy = (uy + 0x7FFFu + ((uy>>16)&1u)) >> 16;
  return (ux & 0xFFFFu) | (uy << 16);
}

template<int L1,int L2,int L>
DEVFN void cg_accum(const float2* F1, const float2* F2, float2* mid){
  constexpr CGList T = build_cg(L1,L2,L);
  #pragma unroll
  for(int e=0;e<T.n;++e){
    const float c = T.coef[e];
    const float2 a = F1[T.mi[e]];
    const float2 b = F2[T.ni[e]];
    float pr = a.x*b.x - a.y*b.y;
    float pim= a.x*b.y + a.y*b.x;
    mid[T.pi[e]].x += c*pr;
    mid[T.pi[e]].y += c*pim;
  }
}

// ===== K1: LDS-staged act; channels (2u,2u+1) share F1; packed mid stores ====
template<int L1,int L2,int L,int PB>
DEVFN void k1_body(const float2* __restrict__ acts, int b0, int u, int bh,
                   float& ssa, float& ssb, unsigned* __restrict__ midw){
  constexpr int N1=2*L1+1, N2=2*L2+1, NP=2*L+1, MLP=MLP_(L);
  constexpr bool SYM = (L1==L2);
  const int t = u>>3, s0 = (u&7)*2;
  unsigned* midl = midw + MBW(L);
  int offA, offB; bool wA, wB;
  if constexpr (SYM){
    const int base = PB + t*16 + s0 - ((t*(t+1))>>1);
    offA = base; offB = base+1;
    wA = (t<=s0); wB = (t<=s0+1);
  } else { offA = PB + 2*u; offB = offA+1; wA = true; wB = true; }
  #pragma unroll 2
  for(int bi=0;bi<8;++bi){
    const int row = bh*8 + bi;
    const float2* arow = acts + row*256;
    float2 F1[N1], F2a[N2], F2b[N2], mida[NP], midb[NP];
    #pragma unroll
    for(int m=0;m<N1;++m) F1[m]=arow[AOFF(L1)+t*N1+m];
    #pragma unroll
    for(int n=0;n<N2;++n){
      F2a[n]=arow[AOFF(L2)+s0*N2+n];
      F2b[n]=arow[AOFF(L2)+(s0+1)*N2+n];
    }
    #pragma unroll
    for(int p=0;p<NP;++p){ mida[p]=make_float2(0.f,0.f); midb[p]=make_float2(0.f,0.f); }
    cg_accum<L1,L2,L>(F1,F2a,mida);
    cg_accum<L1,L2,L>(F1,F2b,midb);
    #pragma unroll
    for(int p=0;p<NP;++p){
      ssa += mida[p].x*mida[p].x + mida[p].y*mida[p].y;
      ssb += midb[p].x*midb[p].x + midb[p].y*midb[p].y;
    }
    {
      const size_t nbase = (size_t)(b0+row)*NP;
      #pragma unroll
      for(int p=0;p<NP;++p){
        unsigned* rp = midl + (nbase+p)*MLP;
        if constexpr (SYM){
          if(wA) __builtin_nontemporal_store(f2bf2(mida[p].x,mida[p].y), rp+offA);
          if(wB) __builtin_nontemporal_store(f2bf2(midb[p].x,midb[p].y), rp+offB);
        } else {
          unsigned long long pv = (unsigned long long)f2bf2(mida[p].x,mida[p].y)
                                | ((unsigned long long)f2bf2(midb[p].x,midb[p].y)<<32);
          __builtin_nontemporal_store(pv, (unsigned long long*)(rp+offA));
        }
      }
    }
  }
}

__global__ __launch_bounds__(256) void k_sumsq(const float* __restrict__ act,
                                               float* __restrict__ sumsq,
                                               unsigned* __restrict__ midw){
  __shared__ float2 acts[16*256];            // 32 KB: 16 act rows
  int bid=blockIdx.x;                        // 23 triples * 128 chunks
  const int order[23] = {22,16,21,18,15,20,13,9,14,8,17,7,12,6,10,3,5,19,2,11,1,4,0};
  int ti = order[bid>>7];
  int b0 = (bid&127)*16;
  const int tid = threadIdx.x;
  {
    const float4* ag = (const float4*)act + (size_t)b0*128;
    float4* as4 = (float4*)acts;
    #pragma unroll
    for(int j=0;j<8;++j) as4[j*256+tid] = ag[j*256+tid];
  }
  __syncthreads();
  const int u = tid & 127, bh = tid >> 7;
  float ssa=0.f, ssb=0.f;
  switch(ti){
    case 0:  k1_body<0,0,0,0>   (acts,b0,u,bh,ssa,ssb,midw); break;
    case 1:  k1_body<1,1,0,136> (acts,b0,u,bh,ssa,ssb,midw); break;
    case 2:  k1_body<2,2,0,272> (acts,b0,u,bh,ssa,ssb,midw); break;
    case 3:  k1_body<3,3,0,408> (acts,b0,u,bh,ssa,ssb,midw); break;
    case 4:  k1_body<1,0,1,0>   (acts,b0,u,bh,ssa,ssb,midw); break;
    case 5:  k1_body<1,1,1,256> (acts,b0,u,bh,ssa,ssb,midw); break;
    case 6:  k1_body<2,1,1,392> (acts,b0,u,bh,ssa,ssb,midw); break;
    case 7:  k1_body<2,2,1,648> (acts,b0,u,bh,ssa,ssb,midw); break;
    case 8:  k1_body<3,2,1,784> (acts,b0,u,bh,ssa,ssb,midw); break;
    case 9:  k1_body<3,3,1,1040>(acts,b0,u,bh,ssa,ssb,midw); break;
    case 10: k1_body<1,1,2,0>   (acts,b0,u,bh,ssa,ssb,midw); break;
    case 11: k1_body<2,0,2,136> (acts,b0,u,bh,ssa,ssb,midw); break;
    case 12: k1_body<2,1,2,392> (acts,b0,u,bh,ssa,ssb,midw); break;
    case 13: k1_body<2,2,2,648> (acts,b0,u,bh,ssa,ssb,midw); break;
    case 14: k1_body<3,1,2,784> (acts,b0,u,bh,ssa,ssb,midw); break;
    case 15: k1_body<3,2,2,1040>(acts,b0,u,bh,ssa,ssb,midw); break;
    case 16: k1_body<3,3,2,1296>(acts,b0,u,bh,ssa,ssb,midw); break;
    case 17: k1_body<2,1,3,0>   (acts,b0,u,bh,ssa,ssb,midw); break;
    case 18: k1_body<2,2,3,256> (acts,b0,u,bh,ssa,ssb,midw); break;
    case 19: k1_body<3,0,3,392> (acts,b0,u,bh,ssa,ssb,midw); break;
    case 20: k1_body<3,1,3,648> (acts,b0,u,bh,ssa,ssb,midw); break;
    case 21: k1_body<3,2,3,904> (acts,b0,u,bh,ssa,ssb,midw); break;
    default: k1_body<3,3,3,1160>(acts,b0,u,bh,ssa,ssb,midw); break;
  }
  atomicAdd(&sumsq[ti*256 + 2*u],     ssa);
  atomicAdd(&sumsq[ti*256 + 2*u + 1], ssb);
}

// ==== K2: scale + build packed bf16 A (mirror weights folded for l1==l2) ====
__global__ __launch_bounds__(256) void k_buildA(const float* __restrict__ W,
                                                const float* __restrict__ bn,
                                                const float* __restrict__ sumsq,
                                                unsigned* __restrict__ A){
  int idx = blockIdx.x*256 + threadIdx.x;   // 5888 original channels
  if(idx>=5888) return;
  int l = (idx<1024)?0 : (idx<2560)?1 : (idx<4352)?2 : 3;
  int c = idx - SOFF(l);
  int q = c>>8, cc = c&255, t = cc>>4, ss = cc&15;
  const unsigned char symf[4][7] = {{1,1,1,1,0,0,0},{0,1,0,1,0,1,0},
                                    {1,0,0,1,0,0,1},{0,1,0,0,0,1,0}};
  const short pbt[4][7] = {{0,136,272,408,0,0,0},{0,256,392,648,784,1040,0},
                           {0,136,392,648,784,1040,1296},{0,256,392,648,904,1160,0}};
  bool sym = symf[l][q];
  if(sym && t>ss) return;                    // mirror folded by (ss,t)-thread
  float divi = (l==0)?(1.f/2048.f) : (l==1)?(1.f/6144.f) : (l==2)?(1.f/10240.f) : (1.f/14336.f);
  float s1 = 1.f/(0.5f*(bn[idx]+sqrtf(sumsq[idx]*divi))+1e-5f);
  int Ml = MLs(l);
  const float2* w1 = (const float2*)W + WOFF(l) + c;
  const float2* w2 = nullptr; float s2 = 0.f;
  if(sym && t<ss){
    int c2 = q*256 + ss*16 + t;
    int i2 = SOFF(l) + c2;
    float sg = (l&1)? -1.f : 1.f;            // mid[s,t] = (-1)^l mid[t,s]
    s2 = sg/(0.5f*(bn[i2]+sqrtf(sumsq[i2]*divi))+1e-5f);
    w2 = (const float2*)W + WOFF(l) + c2;
  }
  int pc = sym ? (pbt[l][q] + t*16+ss - ((t*(t+1))>>1)) : (pbt[l][q] + cc);
  unsigned* Aw = A + ABW(l);
  const int PA = PAW(l);
  for(int o=0;o<16;++o){
    float2 w = w1[(size_t)o*Ml];
    float wex = w.x*s1, wey = w.y*s1;
    if(w2){ float2 v = w2[(size_t)o*Ml]; wex += v.x*s2; wey += v.y*s2; }
    Aw[(size_t)o*PA + pc]      = f2bf2(wex, -wey);
    Aw[(size_t)(o+16)*PA + pc] = f2bf2(wey,  wex);
  }
}

// ======== K6: panel-staged MFMA GEMM (R9 structure, packed K) ========
template<int L>
DEVFN void k6_panel(int tg, const unsigned* __restrict__ midl,
                    const unsigned* __restrict__ Aw, float* __restrict__ out,
                    unsigned* ldsA){
  constexpr int NP = 2*L+1, MLP = MLP_(L), NK = NKc(L), PN = PNc(L), PA = PAW(L);
  const int tid = threadIdx.x;               // 0..511
  const int lane = tid & 63, w = tid >> 6;
  const int col = lane & 15, quad = lane >> 4;
  const int nt = tg*8 + w;
  const unsigned* bp = midl + (size_t)(nt*16 + col)*MLP + quad*4;
  const int r0 = tid >> 5, j0 = (tid & 31)*4, r1 = (tid+512) >> 5;

  f32x4 cR = {0.f,0.f,0.f,0.f};
  f32x4 cI = {0.f,0.f,0.f,0.f};
  {
    uint4 v0 = *(const uint4*)(Aw + (size_t)r0*PA + j0);
    uint4 v1 = *(const uint4*)(Aw + (size_t)r1*PA + j0);
    *(uint4*)(ldsA + r0*APITCH + j0) = v0;
    *(uint4*)(ldsA + r1*APITCH + j0) = v1;
  }
  __syncthreads();
  for(int p=0; p<PN; ++p){
    const unsigned* buf  = ldsA + (p&1)*(32*APITCH);
    unsigned* nbuf = ldsA + ((p+1)&1)*(32*APITCH);
    uint4 v0, v1;
    if(p+1 < PN){
      v0 = *(const uint4*)(Aw + (size_t)r0*PA + (p+1)*128 + j0);
      v1 = *(const uint4*)(Aw + (size_t)r1*PA + (p+1)*128 + j0);
    }
    const unsigned* a0 = buf + col*APITCH + quad*4;
    const unsigned* a1 = buf + (col+16)*APITCH + quad*4;
    #pragma unroll
    for(int c=0; c<8; ++c){
      int kc = p*8 + c; kc = (kc > NK-1) ? NK-1 : kc;   // tail clamp (A=0 there)
      bf16x8 b  = *(const bf16x8*)(bp + (size_t)kc*16);
      bf16x8 A0 = *(const bf16x8*)(a0 + c*16);
      bf16x8 A1 = *(const bf16x8*)(a1 + c*16);
      cR = __builtin_amdgcn_mfma_f32_16x16x32_bf16(A0, b, cR, 0, 0, 0);
      cI = __builtin_amdgcn_mfma_f32_16x16x32_bf16(A1, b, cI, 0, 0, 0);
    }
    if(p+1 < PN){
      *(uint4*)(nbuf + r0*APITCH + j0) = v0;
      *(uint4*)(nbuf + r1*APITCH + j0) = v1;
    }
    __syncthreads();
  }
  const int n = nt*16 + col;
  const int b = n / NP, pp = n % NP;
  float2* out2 = (float2*)out;
  #pragma unroll
  for(int i=0;i<4;++i){
    const int o = quad*4 + i;
    out2[(size_t)b*256 + AOFF(L) + o*NP + pp] = make_float2(cR[i], cI[i]);
  }
}

__global__ __launch_bounds__(512) void k_gemm6(const unsigned* __restrict__ midw,
                                               const unsigned* __restrict__ A,
                                               float* __restrict__ out){
  __shared__ unsigned ldsA[2*32*APITCH];     // 33792 B dbuf
  const int bid = blockIdx.x;                // 256 = 16(l0)+48(l1)+80(l2)+112(l3)
  if(bid < 16)       k6_panel<0>(bid,       midw+MBW(0), A+ABW(0), out, ldsA);
  else if(bid < 64)  k6_panel<1>(bid - 16,  midw+MBW(1), A+ABW(1), out, ldsA);
  else if(bid < 144) k6_panel<2>(bid - 64,  midw+MBW(2), A+ABW(2), out, ldsA);
  else               k6_panel<3>(bid - 144, midw+MBW(3), A+ABW(3), out, ldsA);
}

// ================= host launch =================
extern "C" void kernel_launch(void* const* d_in, const int* in_sizes, int n_in,
                              void* d_out, int out_size, void* d_ws, size_t ws_size,
                              hipStream_t stream) {
  const float* act = (const float*)d_in[0];   // (2048,256,2) f32
  const float* W   = (const float*)d_in[1];   // (94208,2) f32
  const float* bn  = (const float*)d_in[2];   // (5888,) f32
  float* out = (float*)d_out;                 // (2048,256,2) f32

  float*    sumsq = (float*)d_ws;                        // 5888 f32
  unsigned* A     = (unsigned*)((char*)d_ws + 24576);    // 155648 words (623 KB)
  unsigned* midw  = (unsigned*)((char*)d_ws + MID_OFF);  // 166.9 MB packed mid

  hipMemsetAsync(sumsq, 0, 5888*sizeof(float), stream);
  hipMemsetAsync(A, 0, A_WORDS*sizeof(unsigned), stream);  // zero pads/tails
  hipLaunchKernelGGL(k_sumsq,  dim3(23*128), dim3(256), 0, stream, act, sumsq, midw);
  hipLaunchKernelGGL(k_buildA, dim3(23),     dim3(256), 0, stream, W, bn, sumsq, A);
  hipLaunchKernelGGL(k_gemm6,  dim3(256),    dim3(512), 0, stream, midw, A, out);
}

// Round 12
// 178.885 us; speedup vs baseline: 1.0375x; 1.0044x over previous
//
#include <hip/hip_runtime.h>
#include <math.h>

typedef __attribute__((ext_vector_type(8))) short bf16x8;
typedef __attribute__((ext_vector_type(4))) float f32x4;

// ================= compile-time Clebsch-Gordan tables =================
constexpr double cfact(int n){ double r=1.0; for(int i=2;i<=n;++i) r*=(double)i; return r; }
constexpr double csqrt_(double x){ double g=(x>1.0)?x:1.0; for(int i=0;i<100;++i) g=0.5*(g+x/g); return g; }
constexpr double cg_coef_(int l1,int m1,int l2,int m2,int l,int m){
  double pre = csqrt_((double)(2*l+1)*cfact(l1+l2-l)*cfact(l1-l2+l)*cfact(-l1+l2+l)/cfact(l1+l2+l+1));
  pre = pre*csqrt_(cfact(l+m)*cfact(l-m)*cfact(l1-m1)*cfact(l1+m1)*cfact(l2-m2)*cfact(l2+m2));
  double s=0.0;
  for(int k=0;k<=l1+l2-l;++k){
    int d0=k,d1=l1+l2-l-k,d2=l1-m1-k,d3=l2+m2-k,d4=l-l2+m1+k,d5=l-l1-m2+k;
    if(d0<0||d1<0||d2<0||d3<0||d4<0||d5<0) continue;
    double den=cfact(d0)*cfact(d1)*cfact(d2)*cfact(d3)*cfact(d4)*cfact(d5);
    s+=((k&1)?-1.0:1.0)/den;
  }
  return pre*s;
}
struct CGList{ int n; float coef[64]; int mi[64]; int ni[64]; int pi[64]; };
constexpr CGList build_cg(int l1,int l2,int l){
  CGList T{};
  for(int i=0;i<2*l1+1;++i){
    for(int j=0;j<2*l2+1;++j){
      int m1=i-l1, m2=j-l2, m=m1+m2;
      if(m<-l||m>l) continue;
      double c=cg_coef_(l1,m1,l2,m2,l,m);
      if(c>1e-12||c<-1e-12){
        T.coef[T.n]=(float)c; T.mi[T.n]=i; T.ni[T.n]=j; T.pi[T.n]=m+l; T.n++;
      }
    }
  }
  return T;
}

// ================= layout constants =================
__device__ __host__ constexpr int AOFF(int l){ return l==0?0: l==1?16: l==2?64:144; }
__device__ __host__ constexpr int MLs(int l){ return l==0?1024: l==1?1536: l==2?1792:1536; }
__device__ __host__ constexpr int WOFF(int l){ return l==0?0: l==1?16384: l==2?40960:69632; }
__device__ __host__ constexpr int SOFF(int l){ return l==0?0: l==1?1024: l==2?2560:4352; }
// symmetry-packed mid: l1==l2 triples store only t<=s (136 of 256 channels)
__device__ __host__ constexpr int MLP_(int l){ return l==0?544: l==1?1184: l==2?1440:1296; }
__device__ __host__ constexpr size_t MBW(int l){ return l==0?0 : l==1?1114112 : l==2?8388608 : 23134208; }
#define MID_OFF 1048576
#define MID_BYTES ((size_t)41713664*4)
__device__ __host__ constexpr int PAW(int l){ return l==0?640: l==1?1280: l==2?1536:1408; }
__device__ __host__ constexpr int ABW(int l){ return l==0?0: l==1?20480: l==2?61440:110592; }
#define A_WORDS 155648
__device__ __host__ constexpr int NKc(int l){ return MLP_(l)/16; }   // 34/74/90/81
__device__ __host__ constexpr int PNc(int l){ return (NKc(l)+7)/8; } // 5/10/12/11

#define DEVFN __device__ __forceinline__
#define APITCH 132

DEVFN unsigned f2bf2(float x, float y){
  unsigned ux = __float_as_uint(x); ux = (ux + 0x7FFFu + ((ux>>16)&1u)) >> 16;
  unsigned uy = __float_as_uint(y); uy = (uy + 0x7FFFu + ((uy>>16)&1u)) >> 16;
  return (ux & 0xFFFFu) | (uy << 16);
}

template<int L1,int L2,int L>
DEVFN void cg_accum(const float2* F1, const float2* F2, float2* mid){
  constexpr CGList T = build_cg(L1,L2,L);
  #pragma unroll
  for(int e=0;e<T.n;++e){
    const float c = T.coef[e];
    const float2 a = F1[T.mi[e]];
    const float2 b = F2[T.ni[e]];
    float pr = a.x*b.x - a.y*b.y;
    float pim= a.x*b.y + a.y*b.x;
    mid[T.pi[e]].x += c*pr;
    mid[T.pi[e]].y += c*pim;
  }
}

// ===== compile-time unit table: 2224 (triple, channel-pair) units, =====
// ===== heavy triples first; sym triples enumerate only t<=s        =====
struct UArr { unsigned e[2304]; };
constexpr UArr build_units(){
  UArr T{};
  for(int i=0;i<2304;++i) T.e[i]=0xFFFFFFFFu;
  const int ord[23] = {22,16,21,18,15,20,13,9,14,8,17,7,12,6,10,3,5,19,2,11,1,4,0};
  const unsigned char syt[23] = {1,1,1,1,0,1,0,1,0,1,1,0,0,1,0,0,1,0,1,0,0,0,1};
  int n=0;
  for(int oi=0;oi<23;++oi){
    int ti=ord[oi];
    if(syt[ti]){
      for(int t=0;t<16;++t)
        for(int s=t;s+1<=15;s+=2)
          T.e[n++] = (unsigned)((ti<<16)|(t<<12)|(s<<8)|(t<<4)|(s+1));
      for(int t=1;t<=13;t+=4)                 // leftover (t,15) singles paired
        T.e[n++] = (unsigned)((ti<<16)|(t<<12)|(15<<8)|((t+2)<<4)|15);
    } else {
      for(int u=0;u<128;++u){
        int t=u>>3, s0=(u&7)*2;
        T.e[n++] = (unsigned)((ti<<16)|(t<<12)|(s0<<8)|(t<<4)|(s0+1));
      }
    }
  }
  return T;
}
__device__ const UArr d_units = build_units();

// ===== K1 body: two channels (t1,s1),(t2,s2); packed cached stores =====
template<int L1,int L2,int L,int PB>
DEVFN void k1_body(const float2* __restrict__ acts, int b0, int bh,
                   int t1,int s1,int t2,int s2,
                   float& ssa, float& ssb, unsigned* __restrict__ midl){
  constexpr int N1=2*L1+1, N2=2*L2+1, NP=2*L+1, MLP=MLP_(L);
  constexpr bool SYM = (L1==L2);
  const int offA = PB + (SYM ? (t1*16+s1 - ((t1*(t1+1))>>1)) : (t1*16+s1));
  const int offB = PB + (SYM ? (t2*16+s2 - ((t2*(t2+1))>>1)) : (t2*16+s2));
  const bool paired8 = (offB == offA+1) && ((offA & 1) == 0);
  #pragma unroll 2
  for(int bi=0;bi<8;++bi){
    const int row = bh*8 + bi;
    const float2* arow = acts + row*256;
    float2 F1a[N1], F1b[N1], F2a[N2], F2b[N2], mida[NP], midb[NP];
    #pragma unroll
    for(int m=0;m<N1;++m){ F1a[m]=arow[AOFF(L1)+t1*N1+m]; F1b[m]=arow[AOFF(L1)+t2*N1+m]; }
    #pragma unroll
    for(int n=0;n<N2;++n){ F2a[n]=arow[AOFF(L2)+s1*N2+n]; F2b[n]=arow[AOFF(L2)+s2*N2+n]; }
    #pragma unroll
    for(int p=0;p<NP;++p){ mida[p]=make_float2(0.f,0.f); midb[p]=make_float2(0.f,0.f); }
    cg_accum<L1,L2,L>(F1a,F2a,mida);
    cg_accum<L1,L2,L>(F1b,F2b,midb);
    #pragma unroll
    for(int p=0;p<NP;++p){
      ssa += mida[p].x*mida[p].x + mida[p].y*mida[p].y;
      ssb += midb[p].x*midb[p].x + midb[p].y*midb[p].y;
    }
    {
      const size_t nbase = (size_t)(b0+row)*NP;
      #pragma unroll
      for(int p=0;p<NP;++p){
        unsigned va = f2bf2(mida[p].x, mida[p].y);
        unsigned vb = f2bf2(midb[p].x, midb[p].y);
        unsigned* rp = midl + (nbase+p)*MLP;
        if(paired8) *(uint2*)(rp + offA) = make_uint2(va, vb);
        else { rp[offA] = va; rp[offB] = vb; }
      }
    }
  }
}

__global__ __launch_bounds__(256) void k_sumsq(const float* __restrict__ act,
                                               float* __restrict__ sumsq,
                                               unsigned* __restrict__ midw){
  __shared__ float2 acts[16*256];            // 32 KB: 16 act rows
  const int bid = blockIdx.x;                // 18 unit-groups * 128 b-chunks
  const int g = bid>>7, b0 = (bid&127)*16;
  const int tid = threadIdx.x;
  {
    const float4* ag = (const float4*)act + (size_t)b0*128;
    float4* as4 = (float4*)acts;
    #pragma unroll
    for(int j=0;j<8;++j) as4[j*256+tid] = ag[j*256+tid];
  }
  __syncthreads();
  const int v = tid & 127, bh = tid >> 7;
  const unsigned e = d_units.e[g*128 + v];
  if(e == 0xFFFFFFFFu) return;               // after the only barrier: safe
  const int ti=(e>>16)&31, t1=(e>>12)&15, s1=(e>>8)&15, t2=(e>>4)&15, s2=e&15;
  float ssa=0.f, ssb=0.f;
  switch(ti){
    case 0:  k1_body<0,0,0,0>   (acts,b0,bh,t1,s1,t2,s2,ssa,ssb,midw+MBW(0)); break;
    case 1:  k1_body<1,1,0,136> (acts,b0,bh,t1,s1,t2,s2,ssa,ssb,midw+MBW(0)); break;
    case 2:  k1_body<2,2,0,272> (acts,b0,bh,t1,s1,t2,s2,ssa,ssb,midw+MBW(0)); break;
    case 3:  k1_body<3,3,0,408> (acts,b0,bh,t1,s1,t2,s2,ssa,ssb,midw+MBW(0)); break;
    case 4:  k1_body<1,0,1,0>   (acts,b0,bh,t1,s1,t2,s2,ssa,ssb,midw+MBW(1)); break;
    case 5:  k1_body<1,1,1,256> (acts,b0,bh,t1,s1,t2,s2,ssa,ssb,midw+MBW(1)); break;
    case 6:  k1_body<2,1,1,392> (acts,b0,bh,t1,s1,t2,s2,ssa,ssb,midw+MBW(1)); break;
    case 7:  k1_body<2,2,1,648> (acts,b0,bh,t1,s1,t2,s2,ssa,ssb,midw+MBW(1)); break;
    case 8:  k1_body<3,2,1,784> (acts,b0,bh,t1,s1,t2,s2,ssa,ssb,midw+MBW(1)); break;
    case 9:  k1_body<3,3,1,1040>(acts,b0,bh,t1,s1,t2,s2,ssa,ssb,midw+MBW(1)); break;
    case 10: k1_body<1,1,2,0>   (acts,b0,bh,t1,s1,t2,s2,ssa,ssb,midw+MBW(2)); break;
    case 11: k1_body<2,0,2,136> (acts,b0,bh,t1,s1,t2,s2,ssa,ssb,midw+MBW(2)); break;
    case 12: k1_body<2,1,2,392> (acts,b0,bh,t1,s1,t2,s2,ssa,ssb,midw+MBW(2)); break;
    case 13: k1_body<2,2,2,648> (acts,b0,bh,t1,s1,t2,s2,ssa,ssb,midw+MBW(2)); break;
    case 14: k1_body<3,1,2,784> (acts,b0,bh,t1,s1,t2,s2,ssa,ssb,midw+MBW(2)); break;
    case 15: k1_body<3,2,2,1040>(acts,b0,bh,t1,s1,t2,s2,ssa,ssb,midw+MBW(2)); break;
    case 16: k1_body<3,3,2,1296>(acts,b0,bh,t1,s1,t2,s2,ssa,ssb,midw+MBW(2)); break;
    case 17: k1_body<2,1,3,0>   (acts,b0,bh,t1,s1,t2,s2,ssa,ssb,midw+MBW(3)); break;
    case 18: k1_body<2,2,3,256> (acts,b0,bh,t1,s1,t2,s2,ssa,ssb,midw+MBW(3)); break;
    case 19: k1_body<3,0,3,392> (acts,b0,bh,t1,s1,t2,s2,ssa,ssb,midw+MBW(3)); break;
    case 20: k1_body<3,1,3,648> (acts,b0,bh,t1,s1,t2,s2,ssa,ssb,midw+MBW(3)); break;
    case 21: k1_body<3,2,3,904> (acts,b0,bh,t1,s1,t2,s2,ssa,ssb,midw+MBW(3)); break;
    default: k1_body<3,3,3,1160>(acts,b0,bh,t1,s1,t2,s2,ssa,ssb,midw+MBW(3)); break;
  }
  atomicAdd(&sumsq[ti*256 + t1*16 + s1], ssa);
  atomicAdd(&sumsq[ti*256 + t2*16 + s2], ssb);
}

// ==== K2: scale + build packed bf16 A (mirror weights folded for l1==l2;
// ==== mirror batch-std equals representative's: sumsq[t,s]==sumsq[s,t]) ====
__global__ __launch_bounds__(256) void k_buildA(const float* __restrict__ W,
                                                const float* __restrict__ bn,
                                                const float* __restrict__ sumsq,
                                                unsigned* __restrict__ A){
  int idx = blockIdx.x*256 + threadIdx.x;   // 5888 original channels
  if(idx>=5888) return;
  int l = (idx<1024)?0 : (idx<2560)?1 : (idx<4352)?2 : 3;
  int c = idx - SOFF(l);
  int q = c>>8, cc = c&255, t = cc>>4, ss = cc&15;
  const unsigned char symf[4][7] = {{1,1,1,1,0,0,0},{0,1,0,1,0,1,0},
                                    {1,0,0,1,0,0,1},{0,1,0,0,0,1,0}};
  const short pbt[4][7] = {{0,136,272,408,0,0,0},{0,256,392,648,784,1040,0},
                           {0,136,392,648,784,1040,1296},{0,256,392,648,904,1160,0}};
  bool sym = symf[l][q];
  if(sym && t>ss) return;                    // mirror folded by (ss,t)-thread
  float divi = (l==0)?(1.f/2048.f) : (l==1)?(1.f/6144.f) : (l==2)?(1.f/10240.f) : (1.f/14336.f);
  float bstd = sqrtf(sumsq[idx]*divi);
  float s1 = 1.f/(0.5f*(bn[idx]+bstd)+1e-5f);
  int Ml = MLs(l);
  const float2* w1 = (const float2*)W + WOFF(l) + c;
  const float2* w2 = nullptr; float s2 = 0.f;
  if(sym && t<ss){
    int c2 = q*256 + ss*16 + t;
    int i2 = SOFF(l) + c2;
    float sg = (l&1)? -1.f : 1.f;            // mid[s,t] = (-1)^l mid[t,s]
    s2 = sg/(0.5f*(bn[i2]+bstd)+1e-5f);      // same batch-std as representative
    w2 = (const float2*)W + WOFF(l) + c2;
  }
  int pc = sym ? (pbt[l][q] + t*16+ss - ((t*(t+1))>>1)) : (pbt[l][q] + cc);
  unsigned* Aw = A + ABW(l);
  const int PA = PAW(l);
  for(int o=0;o<16;++o){
    float2 w = w1[(size_t)o*Ml];
    float wex = w.x*s1, wey = w.y*s1;
    if(w2){ float2 v = w2[(size_t)o*Ml]; wex += v.x*s2; wey += v.y*s2; }
    Aw[(size_t)o*PA + pc]      = f2bf2(wex, -wey);
    Aw[(size_t)(o+16)*PA + pc] = f2bf2(wey,  wex);
  }
}

// ======== K6: panel-staged MFMA GEMM (R9 structure, packed K) ========
template<int L>
DEVFN void k6_panel(int tg, const unsigned* __restrict__ midl,
                    const unsigned* __restrict__ Aw, float* __restrict__ out,
                    unsigned* ldsA){
  constexpr int NP = 2*L+1, MLP = MLP_(L), NK = NKc(L), PN = PNc(L), PA = PAW(L);
  const int tid = threadIdx.x;               // 0..511
  const int lane = tid & 63, w = tid >> 6;
  const int col = lane & 15, quad = lane >> 4;
  const int nt = tg*8 + w;
  const unsigned* bp = midl + (size_t)(nt*16 + col)*MLP + quad*4;
  const int r0 = tid >> 5, j0 = (tid & 31)*4, r1 = (tid+512) >> 5;

  f32x4 cR = {0.f,0.f,0.f,0.f};
  f32x4 cI = {0.f,0.f,0.f,0.f};
  {
    uint4 v0 = *(const uint4*)(Aw + (size_t)r0*PA + j0);
    uint4 v1 = *(const uint4*)(Aw + (size_t)r1*PA + j0);
    *(uint4*)(ldsA + r0*APITCH + j0) = v0;
    *(uint4*)(ldsA + r1*APITCH + j0) = v1;
  }
  __syncthreads();
  for(int p=0; p<PN; ++p){
    const unsigned* buf  = ldsA + (p&1)*(32*APITCH);
    unsigned* nbuf = ldsA + ((p+1)&1)*(32*APITCH);
    uint4 v0, v1;
    if(p+1 < PN){
      v0 = *(const uint4*)(Aw + (size_t)r0*PA + (p+1)*128 + j0);
      v1 = *(const uint4*)(Aw + (size_t)r1*PA + (p+1)*128 + j0);
    }
    const unsigned* a0 = buf + col*APITCH + quad*4;
    const unsigned* a1 = buf + (col+16)*APITCH + quad*4;
    #pragma unroll
    for(int c=0; c<8; ++c){
      int kc = p*8 + c; kc = (kc > NK-1) ? NK-1 : kc;   // tail clamp (A=0 there)
      bf16x8 b  = *(const bf16x8*)(bp + (size_t)kc*16);
      bf16x8 A0 = *(const bf16x8*)(a0 + c*16);
      bf16x8 A1 = *(const bf16x8*)(a1 + c*16);
      cR = __builtin_amdgcn_mfma_f32_16x16x32_bf16(A0, b, cR, 0, 0, 0);
      cI = __builtin_amdgcn_mfma_f32_16x16x32_bf16(A1, b, cI, 0, 0, 0);
    }
    if(p+1 < PN){
      *(uint4*)(nbuf + r0*APITCH + j0) = v0;
      *(uint4*)(nbuf + r1*APITCH + j0) = v1;
    }
    __syncthreads();
  }
  const int n = nt*16 + col;
  const int b = n / NP, pp = n % NP;
  float2* out2 = (float2*)out;
  #pragma unroll
  for(int i=0;i<4;++i){
    const int o = quad*4 + i;
    out2[(size_t)b*256 + AOFF(L) + o*NP + pp] = make_float2(cR[i], cI[i]);
  }
}

__global__ __launch_bounds__(512) void k_gemm6(const unsigned* __restrict__ midw,
                                               const unsigned* __restrict__ A,
                                               float* __restrict__ out){
  __shared__ unsigned ldsA[2*32*APITCH];     // 33792 B dbuf
  const int bid = blockIdx.x;                // 256 = 16(l0)+48(l1)+80(l2)+112(l3)
  if(bid < 16)       k6_panel<0>(bid,       midw+MBW(0), A+ABW(0), out, ldsA);
  else if(bid < 64)  k6_panel<1>(bid - 16,  midw+MBW(1), A+ABW(1), out, ldsA);
  else if(bid < 144) k6_panel<2>(bid - 64,  midw+MBW(2), A+ABW(2), out, ldsA);
  else               k6_panel<3>(bid - 144, midw+MBW(3), A+ABW(3), out, ldsA);
}

// ================= host launch =================
extern "C" void kernel_launch(void* const* d_in, const int* in_sizes, int n_in,
                              void* d_out, int out_size, void* d_ws, size_t ws_size,
                              hipStream_t stream) {
  const float* act = (const float*)d_in[0];   // (2048,256,2) f32
  const float* W   = (const float*)d_in[1];   // (94208,2) f32
  const float* bn  = (const float*)d_in[2];   // (5888,) f32
  float* out = (float*)d_out;                 // (2048,256,2) f32

  float*    sumsq = (float*)d_ws;                        // 5888 f32
  unsigned* A     = (unsigned*)((char*)d_ws + 24576);    // 155648 words (623 KB)
  unsigned* midw  = (unsigned*)((char*)d_ws + MID_OFF);  // 166.9 MB packed mid

  hipMemsetAsync(sumsq, 0, 5888*sizeof(float), stream);
  hipMemsetAsync(A, 0, A_WORDS*sizeof(unsigned), stream);  // zero pads/tails
  hipLaunchKernelGGL(k_sumsq,  dim3(18*128), dim3(256), 0, stream, act, sumsq, midw);
  hipLaunchKernelGGL(k_buildA, dim3(23),     dim3(256), 0, stream, W, bn, sumsq, A);
  hipLaunchKernelGGL(k_gemm6,  dim3(256),    dim3(512), 0, stream, midw, A, out);
}